// Round 3
// baseline (232.187 us; speedup 1.0000x reference)
//
#include <hip/hip_runtime.h>

// EMA recurrence: out[t] = a*x[t] + (1-a)*out[t-1] over T=4096 (contiguous),
// 8192 independent sequences [B=8, D=1024, T=4096] fp32.
//
// R8: persistent-sequence version. ONE wave per sequence (8192 waves =
// exactly the chip's resident capacity), each scanning its 4096-float row
// in 8 chained 512-float steps. The inter-step carry is EXACT in-register
// (broadcast of lane 63's last output) -- all warm-up re-reads are gone
// (FETCH drops to exactly the 128 MiB input), per-wave setup (exp2f,
// index math, h0 load) is amortized 8x, and the 8-step loop is fully
// unrolled so the step's loads (which do NOT depend on the carry) can be
// issued deep ahead of the compute that consumes them.
//
// R7 post-mortem that motivated this: dur_us = ~160 us of harness reset
// fills (2 x 80 us @ 84% of HBM peak) + ~65 us of ema kernel, vs a 42 us
// traffic floor -- the ema kernel ran at ~65% of the BW the fill kernel
// achieves in the same measurement. The structural difference is wave
// churn with per-wave fixed overhead + 6.25% warm-up read amplification.
//
// Numerics: per 256-float tile, lane-local 4-elem scan + 3-step
// Kogge-Stone over lane tails (weights b^4/b^8/b^16; contributions beyond
// 32 floats truncated, weight <= b^32 ~ 8.4e-8). Carry-in coefficient
// b^(4*lane) underflows to 0 beyond lane ~20 (weight < b^80) -- harmless.
// Inter-tile and inter-step carries are exact.

constexpr int T4 = 1024;   // float4s per sequence (T = 4096 floats)

__global__ __launch_bounds__(256) void ema_seq_kernel(
    const float* __restrict__ x,
    const float* __restrict__ h0,
    float* __restrict__ out,
    int nseq)
{
    const int gtid = blockIdx.x * blockDim.x + threadIdx.x;
    const int w    = gtid >> 6;      // sequence index = wave index
    const int lane = threadIdx.x & 63;
    if (w >= nseq) return;

    const float a   = 0.4f;
    const float b   = 0.6f;
    const float b2  = b * b;
    const float b3  = b2 * b;
    const float b4  = b2 * b2;
    const float b8  = b4 * b4;
    const float b16 = b8 * b8;
    const float inv_b4 = 1.0f / b4;

    // Kogge-Stone step multipliers (0 where no source at that distance).
    const float m1 = (lane >= 1) ? b4  : 0.0f;
    const float m2 = (lane >= 2) ? b8  : 0.0f;
    const float m3 = (lane >= 4) ? b16 : 0.0f;
    // b^(4*lane): carry-in scale; underflows to ~0 beyond lane ~20.
    const float pb4i = exp2f((float)(4 * lane) * -0.73696559416f);

    const float4* __restrict__ xp = (const float4*)x   + (size_t)w * T4 + (size_t)lane;
    float4* __restrict__ op       = (float4*)out       + (size_t)w * T4 + (size_t)lane;

    float h = h0[(size_t)w];         // exact initial hidden state

    // Software pipeline: step 0's tiles loaded up front.
    float4 vA = xp[0];
    float4 vB = xp[64];

    #pragma unroll
    for (int it = 0; it < 8; ++it) {
        // Prefetch next step's tiles (no dependence on the carry chain).
        float4 nA = vA, nB = vB;
        if (it < 7) { nA = xp[128]; nB = xp[192]; }

        // --- lane-local scans (zero-init), 2 independent chains ---
        float a0 = a * vA.x;
        float a1 = fmaf(b, a0, a * vA.y);
        float a2 = fmaf(b, a1, a * vA.z);
        float a3 = fmaf(b, a2, a * vA.w);

        float c0 = a * vB.x;
        float c1 = fmaf(b, c0, a * vB.y);
        float c2 = fmaf(b, c1, a * vB.z);
        float c3 = fmaf(b, c2, a * vB.w);

        // --- Kogge-Stone over lane tails (dist k weight b^(4k), trunc b^32) ---
        float tA = a3, tB = c3, u;
        u = __shfl_up(tA, 1, 64); tA = fmaf(m1, u, tA);
        u = __shfl_up(tB, 1, 64); tB = fmaf(m1, u, tB);
        u = __shfl_up(tA, 2, 64); tA = fmaf(m2, u, tA);
        u = __shfl_up(tB, 2, 64); tB = fmaf(m2, u, tB);
        u = __shfl_up(tA, 4, 64); tA = fmaf(m3, u, tA);
        u = __shfl_up(tB, 4, 64); tB = fmaf(m3, u, tB);

        // --- tile A: exclusive carry recovered algebraically ---
        float eA = fmaf(pb4i, h, (tA - a3) * inv_b4);
        float4 oA;
        oA.x = fmaf(b , eA, a0);
        oA.y = fmaf(b2, eA, a1);
        oA.z = fmaf(b3, eA, a2);
        oA.w = fmaf(b4, eA, a3);

        // Exact carry into tile B: result at float 255 = lane 63's oA.w.
        float h_mid = __shfl(oA.w, 63, 64);

        // --- tile B ---
        float eB = fmaf(pb4i, h_mid, (tB - c3) * inv_b4);
        float4 oB;
        oB.x = fmaf(b , eB, c0);
        oB.y = fmaf(b2, eB, c1);
        oB.z = fmaf(b3, eB, c2);
        oB.w = fmaf(b4, eB, c3);

        op[0]  = oA;
        op[64] = oB;

        // Exact carry into the next 512-float step.
        h = __shfl(oB.w, 63, 64);

        vA = nA; vB = nB;
        xp += 128; op += 128;
    }
}

extern "C" void kernel_launch(void* const* d_in, const int* in_sizes, int n_in,
                              void* d_out, int out_size, void* d_ws, size_t ws_size,
                              hipStream_t stream) {
    const float* x  = (const float*)d_in[0];   // [8,1024,4096] fp32
    const float* h0 = (const float*)d_in[1];   // [8,1024,1]    fp32
    float* out = (float*)d_out;                // [8,1024,4096] fp32

    const int nseq  = in_sizes[1];             // 8192 sequences
    const int block = 256;                     // 4 waves/block
    const long long total = (long long)nseq * 64;
    const int grid = (int)((total + block - 1) / block);  // 2048 blocks

    ema_seq_kernel<<<grid, block, 0, stream>>>(x, h0, out, nseq);
}

// Round 6
// 218.394 us; speedup vs baseline: 1.0632x; 1.0632x over previous
//
#include <hip/hip_runtime.h>

// EMA recurrence: out[t] = a*x[t] + (1-a)*out[t-1] over T=4096 (contiguous),
// 8192 independent sequences [B=8, D=1024, T=4096] fp32.
//
// R11 = restore R5 (the session's best passing kernel, 222.5 us).
// Session ladder (all measured this session):
//   R5  256-float tiles, 131072 waves, max churn        -> 222.5 us  BEST
//   R6/R7 512-float supertiles, 65536 waves             -> 228.6 us
//   R8  persistent, 1 wave/sequence, 8192 waves         -> 232.2 us
//        (ema visible in counters: 2.46 TB/s = 31% peak, VALUBusy 4.5%,
//         occupancy 51% -- latency-bound, NOT BW- or compute-bound)
//   R9/R10 R5 + in-block LDS carry exchange             -> container died
//        (infra degraded monotonically all session; audit found no crash
//         mechanism; expected gain was <= ~2 us since warm-up reads are
//         L2-hits anyway)
// Structural conclusion: churn (many short-lived waves, loads issued at
// wave birth, exit without stalling on anything else) hides load latency
// better than any in-wave pipelining on this chip, and 256-float tiles
// are the churn maximum subject to full float4/lane coalescing.
//
// Design: one wave per 256-float tile, ZERO inter-tile dependency.
//   - Coalesced 64xfloat4 tile load + lanes 0-7 load the preceding 8
//     float4 (warm-up, mostly L2-hit), lane-local scan + Kogge-Stone
//     (3 shuffles), 1 broadcast, coalesced float4 store, exit.
//   - Decay truncation: history older than 32 elements carries weight
//     0.6^32 ~ 8.4e-8 (abs threshold 5.5e-2). Warm-up scan from h=0 over
//     the previous 32 floats replaces the sequential carry. Tile 0 of
//     each sequence uses the true hidden init.

constexpr int TILES_PER_SEQ = 16;    // 4096 / 256

__global__ __launch_bounds__(256) void ema_tile_kernel(
    const float* __restrict__ x,
    const float* __restrict__ h0,
    float* __restrict__ out,
    int ntiles)
{
    const int gtid = blockIdx.x * blockDim.x + threadIdx.x;
    const int w    = gtid >> 6;      // global tile index = wave index
    const int lane = threadIdx.x & 63;
    if (w >= ntiles) return;

    const int tidx = w & (TILES_PER_SEQ - 1);
    const int seq  = w >> 4;

    const float a   = 0.4f;
    const float b   = 0.6f;
    const float b2  = b * b;
    const float b3  = b2 * b;
    const float b4  = b2 * b2;
    const float b8  = b4 * b4;
    const float b16 = b8 * b8;
    const float inv_b4 = 1.0f / b4;

    // Kogge-Stone step multipliers (0 where no source at that distance).
    const float m1 = (lane >= 1) ? b4  : 0.0f;
    const float m2 = (lane >= 2) ? b8  : 0.0f;
    const float m3 = (lane >= 4) ? b16 : 0.0f;
    // b^(4*lane): carry-in scale; underflows to 0 beyond lane ~20 (truncation).
    const float pb4i = exp2f((float)(4 * lane) * -0.73696559416f);

    const float4* __restrict__ xp = (const float4*)x;
    float4* __restrict__ op       = (float4*)out;

    // All flat indices in size_t BEFORE pointer arithmetic.
    const size_t tile_base = (size_t)w * 64;

    // Main tile load: lane i gets floats [w*256 + 4i, ...+4). Fully coalesced.
    float4 v = xp[tile_base + (size_t)lane];

    // Warm-up load: previous 32 floats, lanes 0-7 (wave-uniform branch).
    const bool has_warm = (tidx != 0);
    float4 wv = make_float4(0.f, 0.f, 0.f, 0.f);
    if (has_warm && lane < 8) {
        wv = xp[tile_base - 8 + (size_t)lane];   // tile_base >= 64 here
    }

    // --- main lane-local scan (zero-init): c_j = a*x_j + b*c_{j-1} ---
    float c0 = a * v.x;
    float c1 = fmaf(b, c0, a * v.y);
    float c2 = fmaf(b, c1, a * v.z);
    float c3 = fmaf(b, c2, a * v.w);

    // KS over lane tails (distance k weight b^(4k), truncated at b^32).
    float t = c3, u;
    u = __shfl_up(t, 1, 64); t = fmaf(m1, u, t);
    u = __shfl_up(t, 2, 64); t = fmaf(m2, u, t);
    u = __shfl_up(t, 4, 64); t = fmaf(m3, u, t);

    // --- incoming state h_in at tile start ---
    float h_in;
    if (has_warm) {
        // Scan the 32 warm-up floats (lanes 0-7) from h=0; take lane 7's tail.
        float d0 = a * wv.x;
        float d1 = fmaf(b, d0, a * wv.y);
        float d2 = fmaf(b, d1, a * wv.z);
        float d3 = fmaf(b, d2, a * wv.w);
        float tw = d3;
        u = __shfl_up(tw, 1, 64); tw = fmaf(m1, u, tw);
        u = __shfl_up(tw, 2, 64); tw = fmaf(m2, u, tw);
        u = __shfl_up(tw, 4, 64); tw = fmaf(m3, u, tw);
        h_in = __shfl(tw, 7, 64);
    } else {
        h_in = h0[(size_t)seq];      // true initial hidden state (wave-uniform)
    }

    // Exclusive tail recovered algebraically (dropped term <= b^28 ~ 6e-7).
    float e = fmaf(pb4i, h_in, (t - c3) * inv_b4);

    float4 o;
    o.x = fmaf(b , e, c0);
    o.y = fmaf(b2, e, c1);
    o.z = fmaf(b3, e, c2);
    o.w = fmaf(b4, e, c3);
    op[tile_base + (size_t)lane] = o;
}

extern "C" void kernel_launch(void* const* d_in, const int* in_sizes, int n_in,
                              void* d_out, int out_size, void* d_ws, size_t ws_size,
                              hipStream_t stream) {
    const float* x  = (const float*)d_in[0];   // [8,1024,4096] fp32
    const float* h0 = (const float*)d_in[1];   // [8,1024,1]    fp32
    float* out = (float*)d_out;                // [8,1024,4096] fp32

    const int nseq   = in_sizes[1];            // 8192 sequences
    const int ntiles = nseq * TILES_PER_SEQ;   // 131072 waves
    const int block  = 256;                    // 4 waves/block
    const long long total = (long long)ntiles * 64;
    const int grid = (int)((total + block - 1) / block);  // 32768 blocks

    ema_tile_kernel<<<grid, block, 0, stream>>>(x, h0, out, ntiles);
}